// Round 2
// baseline (939.915 us; speedup 1.0000x reference)
//
#include <hip/hip_runtime.h>

// Neural Additive Model: 256 per-feature MLPs 1->128->64->32->1 (ReLU), summed.
// B=8192, fp32. Compute-bound: 21.8 GMAC -> 278 us floor on the 157 TF vector ALU.
//
// Round 2: round-1 spilled h2[64]/h3[32] to scratch (VGPR_Count=36, 1 GB
// WRITE_SIZE). Fix: named float4 accumulators (cannot be demoted to scratch),
// layer2->3 fused in two k-tiles of 32 so live state = A(32) + G(32) floats.
// Weights are wave-uniform -> s_load + v_fmac_f32(v,s,v), 1 VALU/MAC.
// Grid swizzle: 32 consecutive blocks share a feature -> L2 weight reuse.

typedef float fvec4 __attribute__((ext_vector_type(4)));

#define NF   256
#define NH1  128
#define NH2  64
#define NH3  32
#define NB   8192

__device__ __forceinline__ fvec4 ld4(const float* p) { return *(const fvec4*)p; }
__device__ __forceinline__ float relu(float v) { return fmaxf(v, 0.0f); }
__device__ __forceinline__ fvec4 relu4(fvec4 v) {
    fvec4 r; r.x = relu(v.x); r.y = relu(v.y); r.z = relu(v.z); r.w = relu(v.w);
    return r;
}

__global__ __launch_bounds__(256) void init_out_kernel(float* __restrict__ out,
                                                       const float* __restrict__ bias) {
    int i = blockIdx.x * 256 + threadIdx.x;
    if (i < NB) out[i] = bias[0];
}

// One layer-3 k-row: h2v = relu(acc component), G += h2v * W3[krow][:]
#define L3ONE(val, krow) { \
    const float h2v = relu(val); \
    const float* w3r = w3 + (krow) * NH3; \
    G0 += h2v * ld4(w3r + 0);  G1 += h2v * ld4(w3r + 4); \
    G2 += h2v * ld4(w3r + 8);  G3 += h2v * ld4(w3r + 12); \
    G4 += h2v * ld4(w3r + 16); G5 += h2v * ld4(w3r + 20); \
    G6 += h2v * ld4(w3r + 24); G7 += h2v * ld4(w3r + 28); }

// One k-tile of 32 h2 channels: layer1+2 accumulate, then feed layer 3.
#define KTILE(KT) { \
    const float* bb2t = bb2 + (KT) * 32; \
    fvec4 A0 = ld4(bb2t + 0),  A1 = ld4(bb2t + 4), \
          A2 = ld4(bb2t + 8),  A3 = ld4(bb2t + 12), \
          A4 = ld4(bb2t + 16), A5 = ld4(bb2t + 20), \
          A6 = ld4(bb2t + 24), A7 = ld4(bb2t + 28); \
    _Pragma("unroll 2") \
    for (int j = 0; j < NH1; ++j) { \
        const float h1 = relu(fmaf(xv, w1[j], bb1[j])); \
        const float* w2r = w2 + j * NH2 + (KT) * 32; \
        A0 += h1 * ld4(w2r + 0);  A1 += h1 * ld4(w2r + 4); \
        A2 += h1 * ld4(w2r + 8);  A3 += h1 * ld4(w2r + 12); \
        A4 += h1 * ld4(w2r + 16); A5 += h1 * ld4(w2r + 20); \
        A6 += h1 * ld4(w2r + 24); A7 += h1 * ld4(w2r + 28); \
    } \
    L3ONE(A0.x, (KT)*32 +  0) L3ONE(A0.y, (KT)*32 +  1) L3ONE(A0.z, (KT)*32 +  2) L3ONE(A0.w, (KT)*32 +  3) \
    L3ONE(A1.x, (KT)*32 +  4) L3ONE(A1.y, (KT)*32 +  5) L3ONE(A1.z, (KT)*32 +  6) L3ONE(A1.w, (KT)*32 +  7) \
    L3ONE(A2.x, (KT)*32 +  8) L3ONE(A2.y, (KT)*32 +  9) L3ONE(A2.z, (KT)*32 + 10) L3ONE(A2.w, (KT)*32 + 11) \
    L3ONE(A3.x, (KT)*32 + 12) L3ONE(A3.y, (KT)*32 + 13) L3ONE(A3.z, (KT)*32 + 14) L3ONE(A3.w, (KT)*32 + 15) \
    L3ONE(A4.x, (KT)*32 + 16) L3ONE(A4.y, (KT)*32 + 17) L3ONE(A4.z, (KT)*32 + 18) L3ONE(A4.w, (KT)*32 + 19) \
    L3ONE(A5.x, (KT)*32 + 20) L3ONE(A5.y, (KT)*32 + 21) L3ONE(A5.z, (KT)*32 + 22) L3ONE(A5.w, (KT)*32 + 23) \
    L3ONE(A6.x, (KT)*32 + 24) L3ONE(A6.y, (KT)*32 + 25) L3ONE(A6.z, (KT)*32 + 26) L3ONE(A6.w, (KT)*32 + 27) \
    L3ONE(A7.x, (KT)*32 + 28) L3ONE(A7.y, (KT)*32 + 29) L3ONE(A7.z, (KT)*32 + 30) L3ONE(A7.w, (KT)*32 + 31) }

__global__ __launch_bounds__(256) void nam_kernel(
    const float* __restrict__ x,
    const float* __restrict__ W1, const float* __restrict__ b1,
    const float* __restrict__ W2, const float* __restrict__ b2,
    const float* __restrict__ W3, const float* __restrict__ b3,
    const float* __restrict__ W4, const float* __restrict__ b4,
    float* __restrict__ out)
{
    // 32 consecutive blocks share one feature -> L2 reuse of that feature's
    // weight slice (42 KB) across the 8-XCD round-robin.
    const int f  = blockIdx.x >> 5;            // feature (wave-uniform)
    const int bt = blockIdx.x & 31;            // batch tile
    const int b  = bt * 256 + (int)threadIdx.x;

    const float xv = x[b * NF + f];

    const float* __restrict__ w1  = W1 + f * NH1;
    const float* __restrict__ bb1 = b1 + f * NH1;
    const float* __restrict__ w2  = W2 + f * NH1 * NH2;
    const float* __restrict__ bb2 = b2 + f * NH2;
    const float* __restrict__ w3  = W3 + f * NH2 * NH3;
    const float* __restrict__ bb3 = b3 + f * NH3;
    const float* __restrict__ w4  = W4 + f * NH3;

    // h3 accumulators (persistent across both k-tiles), init with b3.
    fvec4 G0 = ld4(bb3 + 0),  G1 = ld4(bb3 + 4),
          G2 = ld4(bb3 + 8),  G3 = ld4(bb3 + 12),
          G4 = ld4(bb3 + 16), G5 = ld4(bb3 + 20),
          G6 = ld4(bb3 + 24), G7 = ld4(bb3 + 28);

    KTILE(0)
    KTILE(1)

    // ---- layer 4: o = b4[f] + sum_m relu(h3[m]) * W4[m] ----
    fvec4 OV = relu4(G0) * ld4(w4 + 0);
    OV += relu4(G1) * ld4(w4 + 4);
    OV += relu4(G2) * ld4(w4 + 8);
    OV += relu4(G3) * ld4(w4 + 12);
    OV += relu4(G4) * ld4(w4 + 16);
    OV += relu4(G5) * ld4(w4 + 20);
    OV += relu4(G6) * ld4(w4 + 24);
    OV += relu4(G7) * ld4(w4 + 28);
    const float o = b4[f] + ((OV.x + OV.y) + (OV.z + OV.w));

    atomicAdd(&out[b], o);
}

extern "C" void kernel_launch(void* const* d_in, const int* in_sizes, int n_in,
                              void* d_out, int out_size, void* d_ws, size_t ws_size,
                              hipStream_t stream) {
    const float* x    = (const float*)d_in[0];
    const float* W1   = (const float*)d_in[1];
    const float* b1   = (const float*)d_in[2];
    const float* W2   = (const float*)d_in[3];
    const float* b2   = (const float*)d_in[4];
    const float* W3   = (const float*)d_in[5];
    const float* b3   = (const float*)d_in[6];
    const float* W4   = (const float*)d_in[7];
    const float* b4   = (const float*)d_in[8];
    const float* bias = (const float*)d_in[9];
    float* out = (float*)d_out;

    // d_out is poisoned (0xAA) before every launch: initialize to bias.
    init_out_kernel<<<NB / 256, 256, 0, stream>>>(out, bias);

    nam_kernel<<<NF * (NB / 256), 256, 0, stream>>>(
        x, W1, b1, W2, b2, W3, b3, W4, b4, out);
}

// Round 3
// 509.510 us; speedup vs baseline: 1.8447x; 1.8447x over previous
//
#include <hip/hip_runtime.h>

// Neural Additive Model: 256 per-feature MLPs 1->128->64->32->1 (ReLU), summed.
// B=8192, fp32. Compute-bound: 21.8 GMAC.
//   - scalar v_fma_f32 floor: ~290 us; v_pk_fma_f32 (if 2 FMA/lane/2cyc): ~150 us.
//
// Round 3 (fixing round-2 regression):
//   * round 2 macro-expanded ~45 KB of straight-line code -> I$ (32 KB) thrash,
//     VALUBusy 47%. Fix: k-tile is a RUNTIME loop (single code copy, ~10 KB).
//   * round 2 lost FMA contraction (absmax == 0.0 vs np => separate mul+add).
//     Fix: __builtin_elementwise_fma on float2 (also enables v_pk_fma_f32).
//   * named fvec2 accumulators only -> no scratch (round-1 bug stays fixed).
// Weight indices wave-uniform -> s_load; 1 VALU instr per 1-2 MACs.

typedef float fvec2 __attribute__((ext_vector_type(2)));

#define NF   256
#define NH1  128
#define NH2  64
#define NH3  32
#define NB   8192

__device__ __forceinline__ fvec2 ld2(const float* p) { return *(const fvec2*)p; }
__device__ __forceinline__ float relu(float v) { return fmaxf(v, 0.0f); }
// c += a * b, forced FMA (contraction-independent), scalar a broadcast
__device__ __forceinline__ fvec2 fma2s(float a, fvec2 b, fvec2 c) {
    fvec2 av; av.x = a; av.y = a;
    return __builtin_elementwise_fma(av, b, c);
}

__global__ __launch_bounds__(256) void init_out_kernel(float* __restrict__ out,
                                                       const float* __restrict__ bias) {
    int i = blockIdx.x * 256 + threadIdx.x;
    if (i < NB) out[i] = bias[0];
}

// One layer-3 row: G[0:32] += relu(h2val) * W3[krow][0:32]
#define L3ROW(val, krow) { \
    const float h2v = relu(val); \
    const float* w3r = w3t + (krow) * NH3; \
    G0 = fma2s(h2v, ld2(w3r +  0), G0);  G1 = fma2s(h2v, ld2(w3r +  2), G1); \
    G2 = fma2s(h2v, ld2(w3r +  4), G2);  G3 = fma2s(h2v, ld2(w3r +  6), G3); \
    G4 = fma2s(h2v, ld2(w3r +  8), G4);  G5 = fma2s(h2v, ld2(w3r + 10), G5); \
    G6 = fma2s(h2v, ld2(w3r + 12), G6);  G7 = fma2s(h2v, ld2(w3r + 14), G7); \
    G8 = fma2s(h2v, ld2(w3r + 16), G8);  G9 = fma2s(h2v, ld2(w3r + 18), G9); \
    G10 = fma2s(h2v, ld2(w3r + 20), G10); G11 = fma2s(h2v, ld2(w3r + 22), G11); \
    G12 = fma2s(h2v, ld2(w3r + 24), G12); G13 = fma2s(h2v, ld2(w3r + 26), G13); \
    G14 = fma2s(h2v, ld2(w3r + 28), G14); G15 = fma2s(h2v, ld2(w3r + 30), G15); }

__global__ __launch_bounds__(256) void nam_kernel(
    const float* __restrict__ x,
    const float* __restrict__ W1, const float* __restrict__ b1,
    const float* __restrict__ W2, const float* __restrict__ b2,
    const float* __restrict__ W3, const float* __restrict__ b3,
    const float* __restrict__ W4, const float* __restrict__ b4,
    float* __restrict__ out)
{
    // 32 consecutive blocks share one feature -> L2/L3 weight reuse.
    const int f  = blockIdx.x >> 5;            // feature (wave-uniform)
    const int bt = blockIdx.x & 31;            // batch tile
    const int b  = bt * 256 + (int)threadIdx.x;

    const float xv = x[b * NF + f];

    const float* __restrict__ w1  = W1 + f * NH1;
    const float* __restrict__ bb1 = b1 + f * NH1;
    const float* __restrict__ w2  = W2 + f * NH1 * NH2;
    const float* __restrict__ bb2 = b2 + f * NH2;
    const float* __restrict__ w3  = W3 + f * NH2 * NH3;
    const float* __restrict__ bb3 = b3 + f * NH3;
    const float* __restrict__ w4  = W4 + f * NH3;

    // h3 accumulators (32 floats), init with b3.
    fvec2 G0 = ld2(bb3 + 0),  G1 = ld2(bb3 + 2),  G2 = ld2(bb3 + 4),  G3 = ld2(bb3 + 6),
          G4 = ld2(bb3 + 8),  G5 = ld2(bb3 + 10), G6 = ld2(bb3 + 12), G7 = ld2(bb3 + 14),
          G8 = ld2(bb3 + 16), G9 = ld2(bb3 + 18), G10 = ld2(bb3 + 20), G11 = ld2(bb3 + 22),
          G12 = ld2(bb3 + 24), G13 = ld2(bb3 + 26), G14 = ld2(bb3 + 28), G15 = ld2(bb3 + 30);

    // Two k-tiles of 32 h2 channels; RUNTIME loop (single code copy -> fits I$).
    #pragma unroll 1
    for (int kt = 0; kt < 2; ++kt) {
        const int kt32 = kt * 32;
        const float* bb2t = bb2 + kt32;
        const float* w3t  = w3 + kt32 * NH3;

        // layer-2 accumulators for this tile (32 floats), init with b2.
        fvec2 A0 = ld2(bb2t + 0),  A1 = ld2(bb2t + 2),  A2 = ld2(bb2t + 4),  A3 = ld2(bb2t + 6),
              A4 = ld2(bb2t + 8),  A5 = ld2(bb2t + 10), A6 = ld2(bb2t + 12), A7 = ld2(bb2t + 14),
              A8 = ld2(bb2t + 16), A9 = ld2(bb2t + 18), A10 = ld2(bb2t + 20), A11 = ld2(bb2t + 22),
              A12 = ld2(bb2t + 24), A13 = ld2(bb2t + 26), A14 = ld2(bb2t + 28), A15 = ld2(bb2t + 30);

        // layer 1 + 2: A[k] += relu(x*W1[j]+b1[j]) * W2[j][kt32+k]
        #pragma unroll 4
        for (int j = 0; j < NH1; ++j) {
            const float h1 = relu(fmaf(xv, w1[j], bb1[j]));
            const float* w2r = w2 + j * NH2 + kt32;
            A0 = fma2s(h1, ld2(w2r +  0), A0);  A1 = fma2s(h1, ld2(w2r +  2), A1);
            A2 = fma2s(h1, ld2(w2r +  4), A2);  A3 = fma2s(h1, ld2(w2r +  6), A3);
            A4 = fma2s(h1, ld2(w2r +  8), A4);  A5 = fma2s(h1, ld2(w2r + 10), A5);
            A6 = fma2s(h1, ld2(w2r + 12), A6);  A7 = fma2s(h1, ld2(w2r + 14), A7);
            A8 = fma2s(h1, ld2(w2r + 16), A8);  A9 = fma2s(h1, ld2(w2r + 18), A9);
            A10 = fma2s(h1, ld2(w2r + 20), A10); A11 = fma2s(h1, ld2(w2r + 22), A11);
            A12 = fma2s(h1, ld2(w2r + 24), A12); A13 = fma2s(h1, ld2(w2r + 26), A13);
            A14 = fma2s(h1, ld2(w2r + 28), A14); A15 = fma2s(h1, ld2(w2r + 30), A15);
        }

        // layer 3 for this tile's 32 rows (straight-line, but only ONE copy in code)
        L3ROW(A0.x,  0)  L3ROW(A0.y,  1)  L3ROW(A1.x,  2)  L3ROW(A1.y,  3)
        L3ROW(A2.x,  4)  L3ROW(A2.y,  5)  L3ROW(A3.x,  6)  L3ROW(A3.y,  7)
        L3ROW(A4.x,  8)  L3ROW(A4.y,  9)  L3ROW(A5.x, 10)  L3ROW(A5.y, 11)
        L3ROW(A6.x, 12)  L3ROW(A6.y, 13)  L3ROW(A7.x, 14)  L3ROW(A7.y, 15)
        L3ROW(A8.x, 16)  L3ROW(A8.y, 17)  L3ROW(A9.x, 18)  L3ROW(A9.y, 19)
        L3ROW(A10.x, 20) L3ROW(A10.y, 21) L3ROW(A11.x, 22) L3ROW(A11.y, 23)
        L3ROW(A12.x, 24) L3ROW(A12.y, 25) L3ROW(A13.x, 26) L3ROW(A13.y, 27)
        L3ROW(A14.x, 28) L3ROW(A14.y, 29) L3ROW(A15.x, 30) L3ROW(A15.y, 31)
    }

    // layer 4: o = b4[f] + sum_m relu(h3[m]) * W4[m]
    fvec2 OV = {0.0f, 0.0f};
    #define L4(Gi, off) { fvec2 r; r.x = relu(Gi.x); r.y = relu(Gi.y); \
                          OV = __builtin_elementwise_fma(r, ld2(w4 + off), OV); }
    L4(G0, 0)   L4(G1, 2)   L4(G2, 4)   L4(G3, 6)
    L4(G4, 8)   L4(G5, 10)  L4(G6, 12)  L4(G7, 14)
    L4(G8, 16)  L4(G9, 18)  L4(G10, 20) L4(G11, 22)
    L4(G12, 24) L4(G13, 26) L4(G14, 28) L4(G15, 30)
    #undef L4
    const float o = b4[f] + (OV.x + OV.y);

    atomicAdd(&out[b], o);
}

extern "C" void kernel_launch(void* const* d_in, const int* in_sizes, int n_in,
                              void* d_out, int out_size, void* d_ws, size_t ws_size,
                              hipStream_t stream) {
    const float* x    = (const float*)d_in[0];
    const float* W1   = (const float*)d_in[1];
    const float* b1   = (const float*)d_in[2];
    const float* W2   = (const float*)d_in[3];
    const float* b2   = (const float*)d_in[4];
    const float* W3   = (const float*)d_in[5];
    const float* b3   = (const float*)d_in[6];
    const float* W4   = (const float*)d_in[7];
    const float* b4   = (const float*)d_in[8];
    const float* bias = (const float*)d_in[9];
    float* out = (float*)d_out;

    // d_out is poisoned (0xAA) before every launch: initialize to bias.
    init_out_kernel<<<NB / 256, 256, 0, stream>>>(out, bias);

    nam_kernel<<<NF * (NB / 256), 256, 0, stream>>>(
        x, W1, b1, W2, b2, W3, b3, W4, b4, out);
}